// Round 12
// baseline (576.978 us; speedup 1.0000x reference)
//
#include <hip/hip_runtime.h>
#include <math.h>

typedef __attribute__((ext_vector_type(8))) short bf16x8;
typedef __attribute__((ext_vector_type(4))) float f32x4;

__device__ inline unsigned short f2bf(float f) {
    unsigned int u = __float_as_uint(f);
    unsigned int r = u + 0x7fffu + ((u >> 16) & 1u);
    return (unsigned short)(r >> 16);
}
__device__ inline float bf2f(unsigned short b) {
    return __uint_as_float(((unsigned int)b) << 16);
}

// ---------------- CSR build (union graph: nodes [0,N)=g1, [N,2N)=g2) ----------------

__global__ void histU_kernel(const int* __restrict__ d1, const int* __restrict__ d2,
                             int* __restrict__ cnt, int E, int N) {
    int i = blockIdx.x * blockDim.x + threadIdx.x;
    if (i < E) atomicAdd(&cnt[d1[i]], 1);
    else if (i < 2 * E) atomicAdd(&cnt[N + d2[i - E]], 1);
}

__global__ __launch_bounds__(256) void block_reduce_kernel(const int* __restrict__ cnt,
                                                           float* __restrict__ dinv,
                                                           int* __restrict__ blockSums, int NN) {
    int i = blockIdx.x * 256 + threadIdx.x;
    int v = 0;
    if (i < NN) {
        v = cnt[i];
        dinv[i] = 1.0f / sqrtf((float)(v + 1));  // +1 self loop
    }
    int s = v;
#pragma unroll
    for (int o = 32; o; o >>= 1) s += __shfl_down(s, o);
    __shared__ int ws[4];
    if ((threadIdx.x & 63) == 0) ws[threadIdx.x >> 6] = s;
    __syncthreads();
    if (threadIdx.x == 0) blockSums[blockIdx.x] = ws[0] + ws[1] + ws[2] + ws[3];
}

__global__ __launch_bounds__(1024) void scan_sums_kernel(const int* __restrict__ blockSums,
                                                         int* __restrict__ blockOff, int nb,
                                                         int* __restrict__ rowptr, int NN) {
    __shared__ int sh[1024];
    int t = threadIdx.x;
    int v = (t < nb) ? blockSums[t] : 0;
    sh[t] = v;
    __syncthreads();
    for (int o = 1; o < 1024; o <<= 1) {
        int u = (t >= o) ? sh[t - o] : 0;
        __syncthreads();
        sh[t] += u;
        __syncthreads();
    }
    if (t < nb) blockOff[t] = sh[t] - v;
    if (t == 1023) rowptr[NN] = sh[1023];
}

__global__ __launch_bounds__(256) void scan_write_kernel(const int* __restrict__ cnt,
                                                         const int* __restrict__ blockOff,
                                                         int* __restrict__ rowptr, int NN) {
    __shared__ int sh[256];
    int i = blockIdx.x * 256 + threadIdx.x;
    int t = threadIdx.x;
    int v = (i < NN) ? cnt[i] : 0;
    sh[t] = v;
    __syncthreads();
    for (int o = 1; o < 256; o <<= 1) {
        int u = (t >= o) ? sh[t - o] : 0;
        __syncthreads();
        sh[t] += u;
        __syncthreads();
    }
    if (i < NN) rowptr[i] = blockOff[blockIdx.x] + sh[t] - v;
}

__global__ void placeU_kernel(const int* __restrict__ s1, const int* __restrict__ d1,
                              const int* __restrict__ s2, const int* __restrict__ d2,
                              const int* __restrict__ rowptr, int* __restrict__ cnt,
                              int* __restrict__ csr, int E, int N) {
    int i = blockIdx.x * blockDim.x + threadIdx.x;
    int s, d;
    if (i < E)          { s = s1[i];         d = d1[i]; }
    else if (i < 2 * E) { s = s2[i - E] + N; d = d2[i - E] + N; }
    else return;
    int p = atomicSub(&cnt[d], 1);  // old count, 1..deg; drains cnt to 0
    csr[rowptr[d] + p - 1] = s;
}

// ---------------- Weight prep: W[K][128] f32 -> WhT/WlT [128][K] bf16 ----------------

__global__ void prep_weights(const float* __restrict__ W0, const float* __restrict__ W1,
                             const float* __restrict__ W2,
                             unsigned short* __restrict__ W0h, unsigned short* __restrict__ W0l,
                             unsigned short* __restrict__ W1h, unsigned short* __restrict__ W1l,
                             unsigned short* __restrict__ W2h, unsigned short* __restrict__ W2l) {
    const float* W; unsigned short *Wh, *Wl; int K;
    if (blockIdx.x == 0)      { W = W0; Wh = W0h; Wl = W0l; K = 64; }
    else if (blockIdx.x == 1) { W = W1; Wh = W1h; Wl = W1l; K = 128; }
    else                      { W = W2; Wh = W2h; Wl = W2l; K = 128; }
    for (int i = threadIdx.x; i < K * 128; i += 256) {
        int k = i >> 7, c = i & 127;
        float v = W[i];
        unsigned short h = f2bf(v);
        unsigned short l = f2bf(v - bf2f(h));
        Wh[c * K + k] = h;
        Wl[c * K + k] = l;
    }
}

// ---- Prescale: X0[i] = dinv[i] * x(i), unified [NN][64] f32 (coalesced) ----

__global__ void prescale_kernel(const float* __restrict__ x1, const float* __restrict__ x2,
                                const float* __restrict__ dinv, float* __restrict__ X0, int NN,
                                int N) {
    int i = blockIdx.x * blockDim.x + threadIdx.x;  // over NN*16 float4
    if (i >= NN * 16) return;
    int r = i >> 4;
    const float4* src = (r < N) ? (const float4*)(x1) + i
                                : (const float4*)(x2) + (i - N * 16);
    float4 v = *src;
    float d = dinv[r];
    v.x *= d; v.y *= d; v.z *= d; v.w *= d;
    reinterpret_cast<float4*>(X0)[i] = v;
}

// ---- Fused agg + MFMA GEMM (K=64), persistent blocks + dynamic tile stealing.
// Gather: 4 nodes per wave (16-lane groups, float4/lane).

__global__ __launch_bounds__(512) void fused64_agg_gemm(
    const float* __restrict__ X, const int* __restrict__ rowptr,
    const int* __restrict__ csr,
    const unsigned short* __restrict__ WhT, const unsigned short* __restrict__ WlT,
    const float* __restrict__ bias, const float* __restrict__ dinv, int post,
    float* __restrict__ C, int M, int* __restrict__ tileCtr, int nTiles) {
    const int K = 64;
    const int LDA = K + 8;
    __shared__ unsigned short ldsH[64 * LDA];
    __shared__ unsigned short ldsL[64 * LDA];
    __shared__ int sTile;

    int t = threadIdx.x;
    int lane = t & 63, wid = t >> 6;

    const float4* X4 = (const float4*)X;  // 16 float4 per row
    int grp = lane >> 4;   // 0..3
    int fl = lane & 15;

    int c16 = lane & 15, kq = (lane >> 4) * 8;
    int col = wid * 16 + c16;

    while (true) {
        if (t == 0) sTile = atomicAdd(tileCtr, 1);
        __syncthreads();  // broadcast tile + guard LDS reuse from previous iteration
        int tile = sTile;
        if (tile >= nTiles) return;
        int row0 = tile * 64;

        // ---------- phase 1: aggregation (4 nodes per wave pass, 2 passes) ----------
        for (int rr = 0; rr < 2; ++rr) {
            int row = wid * 8 + rr * 4 + grp;
            int g = row0 + row; if (g >= M) g = M - 1;
            int beg = rowptr[g], end = rowptr[g + 1];
            float4 s4 = X4[(size_t)g * 16 + fl];
            float a0 = s4.x, a1 = s4.y, a2 = s4.z, a3 = s4.w;
            int e = beg;
            while (end - e >= 8) {
                int s0 = csr[e], s1 = csr[e + 1], s2 = csr[e + 2], s3 = csr[e + 3];
                int s4i = csr[e + 4], s5 = csr[e + 5], s6 = csr[e + 6], s7 = csr[e + 7];
                float4 v0 = X4[(size_t)s0 * 16 + fl];
                float4 v1 = X4[(size_t)s1 * 16 + fl];
                float4 v2 = X4[(size_t)s2 * 16 + fl];
                float4 v3 = X4[(size_t)s3 * 16 + fl];
                float4 v4 = X4[(size_t)s4i * 16 + fl];
                float4 v5 = X4[(size_t)s5 * 16 + fl];
                float4 v6 = X4[(size_t)s6 * 16 + fl];
                float4 v7 = X4[(size_t)s7 * 16 + fl];
                a0 += ((v0.x + v1.x) + (v2.x + v3.x)) + ((v4.x + v5.x) + (v6.x + v7.x));
                a1 += ((v0.y + v1.y) + (v2.y + v3.y)) + ((v4.y + v5.y) + (v6.y + v7.y));
                a2 += ((v0.z + v1.z) + (v2.z + v3.z)) + ((v4.z + v5.z) + (v6.z + v7.z));
                a3 += ((v0.w + v1.w) + (v2.w + v3.w)) + ((v4.w + v5.w) + (v6.w + v7.w));
                e += 8;
            }
            if (e < end) {
#pragma unroll
                for (int j = 0; j < 7; ++j) {
                    int a = e + j;
                    bool vld = a < end;
                    int s = csr[vld ? a : beg];
                    float m = vld ? 1.f : 0.f;
                    float4 v = X4[(size_t)s * 16 + fl];
                    a0 += m * v.x; a1 += m * v.y; a2 += m * v.z; a3 += m * v.w;
                }
            }
            ushort4 H, L;
            H.x = f2bf(a0); L.x = f2bf(a0 - bf2f(H.x));
            H.y = f2bf(a1); L.y = f2bf(a1 - bf2f(H.y));
            H.z = f2bf(a2); L.z = f2bf(a2 - bf2f(H.z));
            H.w = f2bf(a3); L.w = f2bf(a3 - bf2f(H.w));
            *reinterpret_cast<ushort4*>(&ldsH[row * LDA + fl * 4]) = H;
            *reinterpret_cast<ushort4*>(&ldsL[row * LDA + fl * 4]) = L;
        }
        __syncthreads();

        // ---------- phase 2: MFMA GEMM from LDS ----------
        bf16x8 wh[K / 32], wl[K / 32];
#pragma unroll
        for (int ks = 0; ks < K / 32; ++ks) {
            wh[ks] = *reinterpret_cast<const bf16x8*>(WhT + (size_t)col * K + ks * 32 + kq);
            wl[ks] = *reinterpret_cast<const bf16x8*>(WlT + (size_t)col * K + ks * 32 + kq);
        }
        float bb = bias[col];

#pragma unroll
        for (int rt = 0; rt < 4; ++rt) {
            f32x4 acc = {0.f, 0.f, 0.f, 0.f};
            int abase = (rt * 16 + c16) * LDA + kq;
#pragma unroll
            for (int ks = 0; ks < K / 32; ++ks) {
                bf16x8 ah = *reinterpret_cast<const bf16x8*>(ldsH + abase + ks * 32);
                bf16x8 al = *reinterpret_cast<const bf16x8*>(ldsL + abase + ks * 32);
                acc = __builtin_amdgcn_mfma_f32_16x16x32_bf16(ah, wh[ks], acc, 0, 0, 0);
                acc = __builtin_amdgcn_mfma_f32_16x16x32_bf16(ah, wl[ks], acc, 0, 0, 0);
                acc = __builtin_amdgcn_mfma_f32_16x16x32_bf16(al, wh[ks], acc, 0, 0, 0);
            }
#pragma unroll
            for (int r = 0; r < 4; ++r) {
                int gr = row0 + rt * 16 + (lane >> 4) * 4 + r;
                if (gr < M) {
                    float d = dinv[gr];
                    float po = post ? d : 1.0f;
                    float v = fmaxf(acc[r] * d + bb, 0.f) * po;
                    C[(size_t)gr * 128 + col] = v;
                }
            }
        }
    }
}

// ---- Fused agg + MFMA GEMM (K=128), persistent blocks + dynamic tile stealing.
// Gather: 2 nodes per wave (32-lane groups, float4/lane).

__global__ __launch_bounds__(512) void fused128_agg_gemm(
    const float* __restrict__ X, const int* __restrict__ rowptr,
    const int* __restrict__ csr,
    const unsigned short* __restrict__ WhT, const unsigned short* __restrict__ WlT,
    const float* __restrict__ bias, const float* __restrict__ dinv, int post,
    float* __restrict__ C, int M, int* __restrict__ tileCtr, int nTiles) {
    const int K = 128;
    const int LDA = K + 8;
    __shared__ unsigned short ldsH[64 * LDA];
    __shared__ unsigned short ldsL[64 * LDA];
    __shared__ int sTile;

    int t = threadIdx.x;
    int lane = t & 63, wid = t >> 6;

    const float4* X4 = (const float4*)X;  // 32 float4 per row
    int grp = lane >> 5;   // 0..1
    int fl = lane & 31;

    int c16 = lane & 15, kq = (lane >> 4) * 8;
    int col = wid * 16 + c16;

    while (true) {
        if (t == 0) sTile = atomicAdd(tileCtr, 1);
        __syncthreads();  // broadcast tile + guard LDS reuse from previous iteration
        int tile = sTile;
        if (tile >= nTiles) return;
        int row0 = tile * 64;

        // ---------- phase 1: aggregation (2 nodes per wave pass, 4 passes) ----------
        for (int rr = 0; rr < 4; ++rr) {
            int row = wid * 8 + rr * 2 + grp;
            int g = row0 + row; if (g >= M) g = M - 1;
            int beg = rowptr[g], end = rowptr[g + 1];
            float4 s4 = X4[(size_t)g * 32 + fl];
            float a0 = s4.x, a1 = s4.y, a2 = s4.z, a3 = s4.w;
            int e = beg;
            while (end - e >= 8) {
                int s0 = csr[e], s1 = csr[e + 1], s2 = csr[e + 2], s3 = csr[e + 3];
                int s4i = csr[e + 4], s5 = csr[e + 5], s6 = csr[e + 6], s7 = csr[e + 7];
                float4 v0 = X4[(size_t)s0 * 32 + fl];
                float4 v1 = X4[(size_t)s1 * 32 + fl];
                float4 v2 = X4[(size_t)s2 * 32 + fl];
                float4 v3 = X4[(size_t)s3 * 32 + fl];
                float4 v4 = X4[(size_t)s4i * 32 + fl];
                float4 v5 = X4[(size_t)s5 * 32 + fl];
                float4 v6 = X4[(size_t)s6 * 32 + fl];
                float4 v7 = X4[(size_t)s7 * 32 + fl];
                a0 += ((v0.x + v1.x) + (v2.x + v3.x)) + ((v4.x + v5.x) + (v6.x + v7.x));
                a1 += ((v0.y + v1.y) + (v2.y + v3.y)) + ((v4.y + v5.y) + (v6.y + v7.y));
                a2 += ((v0.z + v1.z) + (v2.z + v3.z)) + ((v4.z + v5.z) + (v6.z + v7.z));
                a3 += ((v0.w + v1.w) + (v2.w + v3.w)) + ((v4.w + v5.w) + (v6.w + v7.w));
                e += 8;
            }
            if (e < end) {
#pragma unroll
                for (int j = 0; j < 7; ++j) {
                    int a = e + j;
                    bool vld = a < end;
                    int s = csr[vld ? a : beg];
                    float m = vld ? 1.f : 0.f;
                    float4 v = X4[(size_t)s * 32 + fl];
                    a0 += m * v.x; a1 += m * v.y; a2 += m * v.z; a3 += m * v.w;
                }
            }
            ushort4 H, L;
            H.x = f2bf(a0); L.x = f2bf(a0 - bf2f(H.x));
            H.y = f2bf(a1); L.y = f2bf(a1 - bf2f(H.y));
            H.z = f2bf(a2); L.z = f2bf(a2 - bf2f(H.z));
            H.w = f2bf(a3); L.w = f2bf(a3 - bf2f(H.w));
            *reinterpret_cast<ushort4*>(&ldsH[row * LDA + fl * 4]) = H;
            *reinterpret_cast<ushort4*>(&ldsL[row * LDA + fl * 4]) = L;
        }
        __syncthreads();

        // ---------- phase 2: MFMA GEMM from LDS ----------
        bf16x8 wh[K / 32], wl[K / 32];
#pragma unroll
        for (int ks = 0; ks < K / 32; ++ks) {
            wh[ks] = *reinterpret_cast<const bf16x8*>(WhT + (size_t)col * K + ks * 32 + kq);
            wl[ks] = *reinterpret_cast<const bf16x8*>(WlT + (size_t)col * K + ks * 32 + kq);
        }
        float bb = bias[col];

#pragma unroll
        for (int rt = 0; rt < 4; ++rt) {
            f32x4 acc = {0.f, 0.f, 0.f, 0.f};
            int abase = (rt * 16 + c16) * LDA + kq;
#pragma unroll
            for (int ks = 0; ks < K / 32; ++ks) {
                bf16x8 ah = *reinterpret_cast<const bf16x8*>(ldsH + abase + ks * 32);
                bf16x8 al = *reinterpret_cast<const bf16x8*>(ldsL + abase + ks * 32);
                acc = __builtin_amdgcn_mfma_f32_16x16x32_bf16(ah, wh[ks], acc, 0, 0, 0);
                acc = __builtin_amdgcn_mfma_f32_16x16x32_bf16(ah, wl[ks], acc, 0, 0, 0);
                acc = __builtin_amdgcn_mfma_f32_16x16x32_bf16(al, wh[ks], acc, 0, 0, 0);
            }
#pragma unroll
            for (int r = 0; r < 4; ++r) {
                int gr = row0 + rt * 16 + (lane >> 4) * 4 + r;
                if (gr < M) {
                    float d = dinv[gr];
                    float po = post ? d : 1.0f;
                    float v = fmaxf(acc[r] * d + bb, 0.f) * po;
                    C[(size_t)gr * 128 + col] = v;
                }
            }
        }
    }
}

// ---------------- Final FC ----------------

__global__ void fc_kernel(const float* __restrict__ H3, const int* __restrict__ label,
                          const float* __restrict__ fcW, const float* __restrict__ fcb,
                          float* __restrict__ out, int P, int N) {
    int w = blockIdx.x * (blockDim.x >> 6) + (threadIdx.x >> 6);
    int lane = threadIdx.x & 63;
    if (w >= P) return;
    int l0 = label[2 * w], l1 = label[2 * w + 1] + N;
    float xl0 = H3[(size_t)l0 * 128 + lane];
    float xl1 = H3[(size_t)l0 * 128 + 64 + lane];
    float xr0 = H3[(size_t)l1 * 128 + lane];
    float xr1 = H3[(size_t)l1 * 128 + 64 + lane];
    float a0 = xl0 * fcW[lane * 2]             + xl1 * fcW[(64 + lane) * 2]
             + xr0 * fcW[(128 + lane) * 2]     + xr1 * fcW[(192 + lane) * 2];
    float a1 = xl0 * fcW[lane * 2 + 1]         + xl1 * fcW[(64 + lane) * 2 + 1]
             + xr0 * fcW[(128 + lane) * 2 + 1] + xr1 * fcW[(192 + lane) * 2 + 1];
#pragma unroll
    for (int o = 32; o; o >>= 1) {
        a0 += __shfl_xor(a0, o);
        a1 += __shfl_xor(a1, o);
    }
    if (lane == 0) {
        out[2 * w]     = fmaxf(a0 + fcb[0], 0.f);
        out[2 * w + 1] = fmaxf(a1 + fcb[1], 0.f);
    }
}

// ---------------- launch ----------------

extern "C" void kernel_launch(void* const* d_in, const int* in_sizes, int n_in,
                              void* d_out, int out_size, void* d_ws, size_t ws_size,
                              hipStream_t stream) {
    const float* x1   = (const float*)d_in[0];
    const int*   e1   = (const int*)d_in[1];
    const float* x2   = (const float*)d_in[2];
    const int*   e2   = (const int*)d_in[3];
    const int*   label= (const int*)d_in[4];
    const float* W0   = (const float*)d_in[5];
    const float* b0   = (const float*)d_in[6];
    const float* W1   = (const float*)d_in[7];
    const float* b1   = (const float*)d_in[8];
    const float* W2   = (const float*)d_in[9];
    const float* b2   = (const float*)d_in[10];
    const float* fcW  = (const float*)d_in[11];
    const float* fcb  = (const float*)d_in[12];
    float* out = (float*)d_out;

    const int N = in_sizes[0] / 64;
    const int E = in_sizes[1] / 2;
    const int P = in_sizes[4] / 2;
    const int NN = 2 * N;
    const int NB = (NN + 255) / 256;
    const int GB = (NN + 63) / 64;          // tiles (64 rows each)
    const int PB64 = (GB < 2048) ? GB : 2048;   // persistent blocks, fused64 (LDS 18KB -> 8/CU)
    const int PB128 = (GB < 1024) ? GB : 1024;  // persistent blocks, fused128 (LDS 35KB -> 4/CU)

    char* ws = (char*)d_ws;
    size_t off = 0;
    auto alloc = [&](size_t bytes) -> void* {
        void* p = ws + off;
        off += (bytes + 255) & ~(size_t)255;
        return p;
    };
    int*   cnt      = (int*)alloc((size_t)(NN + 16) * 4);  // +16: tile counters at cnt[NN..]
    int*   rowptr   = (int*)alloc((size_t)(NN + 1) * 4);
    float* dinv     = (float*)alloc((size_t)NN * 4);
    int*   csr      = (int*)alloc((size_t)2 * E * 4);
    int*   blockSums= (int*)alloc((size_t)NB * 4);
    int*   blockOff = (int*)alloc((size_t)NB * 4);
    float* bufA     = (float*)alloc((size_t)NN * 128 * 4);  // X0 ([NN][64]) then H2
    float* bufB     = (float*)alloc((size_t)NN * 128 * 4);  // H1 then H3
    unsigned short* W0h = (unsigned short*)alloc(64 * 128 * 2);
    unsigned short* W0l = (unsigned short*)alloc(64 * 128 * 2);
    unsigned short* W1h = (unsigned short*)alloc(128 * 128 * 2);
    unsigned short* W1l = (unsigned short*)alloc(128 * 128 * 2);
    unsigned short* W2h = (unsigned short*)alloc(128 * 128 * 2);
    unsigned short* W2l = (unsigned short*)alloc(128 * 128 * 2);
    int* ctr = cnt + NN;  // 3 tile counters, zeroed by the memset below each call

    prep_weights<<<3, 256, 0, stream>>>(W0, W1, W2, W0h, W0l, W1h, W1l, W2h, W2l);

    // CSR build (once, union graph); memset also zeroes the tile counters
    hipMemsetAsync(cnt, 0, (size_t)(NN + 16) * 4, stream);
    histU_kernel<<<(2 * E + 255) / 256, 256, 0, stream>>>(e1 + E, e2 + E, cnt, E, N);
    block_reduce_kernel<<<NB, 256, 0, stream>>>(cnt, dinv, blockSums, NN);
    scan_sums_kernel<<<1, 1024, 0, stream>>>(blockSums, blockOff, NB, rowptr, NN);
    scan_write_kernel<<<NB, 256, 0, stream>>>(cnt, blockOff, rowptr, NN);
    placeU_kernel<<<(2 * E + 255) / 256, 256, 0, stream>>>(e1, e1 + E, e2, e2 + E,
                                                           rowptr, cnt, csr, E, N);
    // layer 0: prescale into X0 (bufA), fused agg+GEMM 64->128 into bufB
    prescale_kernel<<<(NN * 16 + 255) / 256, 256, 0, stream>>>(x1, x2, dinv, bufA, NN, N);
    fused64_agg_gemm<<<PB64, 512, 0, stream>>>(bufA, rowptr, csr, W0h, W0l, b0, dinv, 1,
                                               bufB, NN, ctr + 0, GB);
    // layer 1: bufB -> bufA
    fused128_agg_gemm<<<PB128, 512, 0, stream>>>(bufB, rowptr, csr, W1h, W1l, b1, dinv, 1,
                                                 bufA, NN, ctr + 1, GB);
    // layer 2 (no post-scale): bufA -> bufB (H3)
    fused128_agg_gemm<<<PB128, 512, 0, stream>>>(bufA, rowptr, csr, W2h, W2l, b2, dinv, 0,
                                                 bufB, NN, ctr + 2, GB);

    fc_kernel<<<(P + 3) / 4, 256, 0, stream>>>(bufB, label, fcW, fcb, out, P, N);
}

// Round 13
// 541.229 us; speedup vs baseline: 1.0661x; 1.0661x over previous
//
#include <hip/hip_runtime.h>
#include <math.h>

typedef __attribute__((ext_vector_type(8))) short bf16x8;
typedef __attribute__((ext_vector_type(4))) float f32x4;

__device__ inline unsigned short f2bf(float f) {
    unsigned int u = __float_as_uint(f);
    unsigned int r = u + 0x7fffu + ((u >> 16) & 1u);
    return (unsigned short)(r >> 16);
}
__device__ inline float bf2f(unsigned short b) {
    return __uint_as_float(((unsigned int)b) << 16);
}

// ---------------- CSR build (union graph: nodes [0,N)=g1, [N,2N)=g2) ----------------

__global__ void histU_kernel(const int* __restrict__ d1, const int* __restrict__ d2,
                             int* __restrict__ cnt, int E, int N) {
    int i = blockIdx.x * blockDim.x + threadIdx.x;
    if (i < E) atomicAdd(&cnt[d1[i]], 1);
    else if (i < 2 * E) atomicAdd(&cnt[N + d2[i - E]], 1);
}

__global__ __launch_bounds__(256) void block_reduce_kernel(const int* __restrict__ cnt,
                                                           float* __restrict__ dinv,
                                                           int* __restrict__ blockSums, int NN) {
    int i = blockIdx.x * 256 + threadIdx.x;
    int v = 0;
    if (i < NN) {
        v = cnt[i];
        dinv[i] = 1.0f / sqrtf((float)(v + 1));  // +1 self loop
    }
    int s = v;
#pragma unroll
    for (int o = 32; o; o >>= 1) s += __shfl_down(s, o);
    __shared__ int ws[4];
    if ((threadIdx.x & 63) == 0) ws[threadIdx.x >> 6] = s;
    __syncthreads();
    if (threadIdx.x == 0) blockSums[blockIdx.x] = ws[0] + ws[1] + ws[2] + ws[3];
}

__global__ __launch_bounds__(1024) void scan_sums_kernel(const int* __restrict__ blockSums,
                                                         int* __restrict__ blockOff, int nb,
                                                         int* __restrict__ rowptr, int NN) {
    __shared__ int sh[1024];
    int t = threadIdx.x;
    int v = (t < nb) ? blockSums[t] : 0;
    sh[t] = v;
    __syncthreads();
    for (int o = 1; o < 1024; o <<= 1) {
        int u = (t >= o) ? sh[t - o] : 0;
        __syncthreads();
        sh[t] += u;
        __syncthreads();
    }
    if (t < nb) blockOff[t] = sh[t] - v;
    if (t == 1023) rowptr[NN] = sh[1023];
}

__global__ __launch_bounds__(256) void scan_write_kernel(const int* __restrict__ cnt,
                                                         const int* __restrict__ blockOff,
                                                         int* __restrict__ rowptr, int NN) {
    __shared__ int sh[256];
    int i = blockIdx.x * 256 + threadIdx.x;
    int t = threadIdx.x;
    int v = (i < NN) ? cnt[i] : 0;
    sh[t] = v;
    __syncthreads();
    for (int o = 1; o < 256; o <<= 1) {
        int u = (t >= o) ? sh[t - o] : 0;
        __syncthreads();
        sh[t] += u;
        __syncthreads();
    }
    if (i < NN) rowptr[i] = blockOff[blockIdx.x] + sh[t] - v;
}

__global__ void placeU_kernel(const int* __restrict__ s1, const int* __restrict__ d1,
                              const int* __restrict__ s2, const int* __restrict__ d2,
                              const int* __restrict__ rowptr, int* __restrict__ cnt,
                              int* __restrict__ csr, int E, int N) {
    int i = blockIdx.x * blockDim.x + threadIdx.x;
    int s, d;
    if (i < E)          { s = s1[i];         d = d1[i]; }
    else if (i < 2 * E) { s = s2[i - E] + N; d = d2[i - E] + N; }
    else return;
    int p = atomicSub(&cnt[d], 1);  // old count, 1..deg; drains cnt to 0
    csr[rowptr[d] + p - 1] = s;
}

// ---------------- Weight prep: W[K][128] f32 -> WhT/WlT [128][K] bf16 ----------------

__global__ void prep_weights(const float* __restrict__ W0, const float* __restrict__ W1,
                             const float* __restrict__ W2,
                             unsigned short* __restrict__ W0h, unsigned short* __restrict__ W0l,
                             unsigned short* __restrict__ W1h, unsigned short* __restrict__ W1l,
                             unsigned short* __restrict__ W2h, unsigned short* __restrict__ W2l) {
    const float* W; unsigned short *Wh, *Wl; int K;
    if (blockIdx.x == 0)      { W = W0; Wh = W0h; Wl = W0l; K = 64; }
    else if (blockIdx.x == 1) { W = W1; Wh = W1h; Wl = W1l; K = 128; }
    else                      { W = W2; Wh = W2h; Wl = W2l; K = 128; }
    for (int i = threadIdx.x; i < K * 128; i += 256) {
        int k = i >> 7, c = i & 127;
        float v = W[i];
        unsigned short h = f2bf(v);
        unsigned short l = f2bf(v - bf2f(h));
        Wh[c * K + k] = h;
        Wl[c * K + k] = l;
    }
}

// ---- Prescale: X0[i] = dinv[i] * x(i), unified [NN][64] f32 (coalesced) ----

__global__ void prescale_kernel(const float* __restrict__ x1, const float* __restrict__ x2,
                                const float* __restrict__ dinv, float* __restrict__ X0, int NN,
                                int N) {
    int i = blockIdx.x * blockDim.x + threadIdx.x;  // over NN*16 float4
    if (i >= NN * 16) return;
    int r = i >> 4;
    const float4* src = (r < N) ? (const float4*)(x1) + i
                                : (const float4*)(x2) + (i - N * 16);
    float4 v = *src;
    float d = dinv[r];
    v.x *= d; v.y *= d; v.z *= d; v.w *= d;
    reinterpret_cast<float4*>(X0)[i] = v;
}

// ---- Fused agg + MFMA GEMM (K=64). Block = 64 rows, 512 thr = 8 waves.
// Gather: 4 nodes per wave (16-lane groups, float4/lane = full 64-f32 row per group).

__global__ __launch_bounds__(512) void fused64_agg_gemm(
    const float* __restrict__ X, const int* __restrict__ rowptr,
    const int* __restrict__ csr,
    const unsigned short* __restrict__ WhT, const unsigned short* __restrict__ WlT,
    const float* __restrict__ bias, const float* __restrict__ dinv, int post,
    float* __restrict__ C, int M) {
    const int K = 64;
    const int LDA = K + 8;
    __shared__ unsigned short ldsH[64 * LDA];
    __shared__ unsigned short ldsL[64 * LDA];

    int t = threadIdx.x;
    int lane = t & 63, wid = t >> 6;
    int row0 = blockIdx.x * 64;

    const float4* X4 = (const float4*)X;  // 16 float4 per row
    int grp = lane >> 4;   // 0..3
    int fl = lane & 15;    // features fl*4 .. fl*4+3

    // ---------- phase 1: aggregation (4 nodes per wave pass, 2 passes) ----------
    for (int rr = 0; rr < 2; ++rr) {
        int row = wid * 8 + rr * 4 + grp;
        int g = row0 + row; if (g >= M) g = M - 1;
        int beg = rowptr[g], end = rowptr[g + 1];
        float4 s4 = X4[(size_t)g * 16 + fl];
        float a0 = s4.x, a1 = s4.y, a2 = s4.z, a3 = s4.w;
        int e = beg;
        while (end - e >= 8) {  // per-group divergence via exec mask; loads stay clean
            int s0 = csr[e], s1 = csr[e + 1], s2 = csr[e + 2], s3 = csr[e + 3];
            int s4i = csr[e + 4], s5 = csr[e + 5], s6 = csr[e + 6], s7 = csr[e + 7];
            float4 v0 = X4[(size_t)s0 * 16 + fl];
            float4 v1 = X4[(size_t)s1 * 16 + fl];
            float4 v2 = X4[(size_t)s2 * 16 + fl];
            float4 v3 = X4[(size_t)s3 * 16 + fl];
            float4 v4 = X4[(size_t)s4i * 16 + fl];
            float4 v5 = X4[(size_t)s5 * 16 + fl];
            float4 v6 = X4[(size_t)s6 * 16 + fl];
            float4 v7 = X4[(size_t)s7 * 16 + fl];
            a0 += ((v0.x + v1.x) + (v2.x + v3.x)) + ((v4.x + v5.x) + (v6.x + v7.x));
            a1 += ((v0.y + v1.y) + (v2.y + v3.y)) + ((v4.y + v5.y) + (v6.y + v7.y));
            a2 += ((v0.z + v1.z) + (v2.z + v3.z)) + ((v4.z + v5.z) + (v6.z + v7.z));
            a3 += ((v0.w + v1.w) + (v2.w + v3.w)) + ((v4.w + v5.w) + (v6.w + v7.w));
            e += 8;
        }
        if (e < end) {  // masked tail, up to 7 in flight
#pragma unroll
            for (int j = 0; j < 7; ++j) {
                int a = e + j;
                bool vld = a < end;
                int s = csr[vld ? a : beg];
                float m = vld ? 1.f : 0.f;
                float4 v = X4[(size_t)s * 16 + fl];
                a0 += m * v.x; a1 += m * v.y; a2 += m * v.z; a3 += m * v.w;
            }
        }
        ushort4 H, L;
        H.x = f2bf(a0); L.x = f2bf(a0 - bf2f(H.x));
        H.y = f2bf(a1); L.y = f2bf(a1 - bf2f(H.y));
        H.z = f2bf(a2); L.z = f2bf(a2 - bf2f(H.z));
        H.w = f2bf(a3); L.w = f2bf(a3 - bf2f(H.w));
        *reinterpret_cast<ushort4*>(&ldsH[row * LDA + fl * 4]) = H;
        *reinterpret_cast<ushort4*>(&ldsL[row * LDA + fl * 4]) = L;
    }
    __syncthreads();

    // ---------- phase 2: MFMA GEMM from LDS ----------
    int c16 = lane & 15, kq = (lane >> 4) * 8;
    int col = wid * 16 + c16;

    bf16x8 wh[K / 32], wl[K / 32];
#pragma unroll
    for (int ks = 0; ks < K / 32; ++ks) {
        wh[ks] = *reinterpret_cast<const bf16x8*>(WhT + (size_t)col * K + ks * 32 + kq);
        wl[ks] = *reinterpret_cast<const bf16x8*>(WlT + (size_t)col * K + ks * 32 + kq);
    }
    float bb = bias[col];

#pragma unroll
    for (int rt = 0; rt < 4; ++rt) {
        f32x4 acc = {0.f, 0.f, 0.f, 0.f};
        int abase = (rt * 16 + c16) * LDA + kq;
#pragma unroll
        for (int ks = 0; ks < K / 32; ++ks) {
            bf16x8 ah = *reinterpret_cast<const bf16x8*>(ldsH + abase + ks * 32);
            bf16x8 al = *reinterpret_cast<const bf16x8*>(ldsL + abase + ks * 32);
            acc = __builtin_amdgcn_mfma_f32_16x16x32_bf16(ah, wh[ks], acc, 0, 0, 0);
            acc = __builtin_amdgcn_mfma_f32_16x16x32_bf16(ah, wl[ks], acc, 0, 0, 0);
            acc = __builtin_amdgcn_mfma_f32_16x16x32_bf16(al, wh[ks], acc, 0, 0, 0);
        }
#pragma unroll
        for (int r = 0; r < 4; ++r) {
            int gr = row0 + rt * 16 + (lane >> 4) * 4 + r;
            if (gr < M) {
                float d = dinv[gr];
                float po = post ? d : 1.0f;
                float v = fmaxf(acc[r] * d + bb, 0.f) * po;
                C[(size_t)gr * 128 + col] = v;
            }
        }
    }
}

// ---- Fused agg + MFMA GEMM (K=128). Gather: 2 nodes per wave (32-lane groups, float4). ----

__global__ __launch_bounds__(512) void fused128_agg_gemm(
    const float* __restrict__ X, const int* __restrict__ rowptr,
    const int* __restrict__ csr,
    const unsigned short* __restrict__ WhT, const unsigned short* __restrict__ WlT,
    const float* __restrict__ bias, const float* __restrict__ dinv, int post,
    float* __restrict__ C, int M) {
    const int K = 128;
    const int LDA = K + 8;
    __shared__ unsigned short ldsH[64 * LDA];
    __shared__ unsigned short ldsL[64 * LDA];

    int t = threadIdx.x;
    int lane = t & 63, wid = t >> 6;
    int row0 = blockIdx.x * 64;

    const float4* X4 = (const float4*)X;  // 32 float4 per row
    int grp = lane >> 5;   // 0..1
    int fl = lane & 31;    // features fl*4 .. fl*4+3

    // ---------- phase 1: aggregation (2 nodes per wave pass, 4 passes) ----------
    for (int rr = 0; rr < 4; ++rr) {
        int row = wid * 8 + rr * 2 + grp;
        int g = row0 + row; if (g >= M) g = M - 1;
        int beg = rowptr[g], end = rowptr[g + 1];
        float4 s4 = X4[(size_t)g * 32 + fl];
        float a0 = s4.x, a1 = s4.y, a2 = s4.z, a3 = s4.w;
        int e = beg;
        while (end - e >= 8) {  // per-group divergence via exec mask; loads stay clean
            int s0 = csr[e], s1 = csr[e + 1], s2 = csr[e + 2], s3 = csr[e + 3];
            int s4i = csr[e + 4], s5 = csr[e + 5], s6 = csr[e + 6], s7 = csr[e + 7];
            float4 v0 = X4[(size_t)s0 * 32 + fl];
            float4 v1 = X4[(size_t)s1 * 32 + fl];
            float4 v2 = X4[(size_t)s2 * 32 + fl];
            float4 v3 = X4[(size_t)s3 * 32 + fl];
            float4 v4 = X4[(size_t)s4i * 32 + fl];
            float4 v5 = X4[(size_t)s5 * 32 + fl];
            float4 v6 = X4[(size_t)s6 * 32 + fl];
            float4 v7 = X4[(size_t)s7 * 32 + fl];
            a0 += ((v0.x + v1.x) + (v2.x + v3.x)) + ((v4.x + v5.x) + (v6.x + v7.x));
            a1 += ((v0.y + v1.y) + (v2.y + v3.y)) + ((v4.y + v5.y) + (v6.y + v7.y));
            a2 += ((v0.z + v1.z) + (v2.z + v3.z)) + ((v4.z + v5.z) + (v6.z + v7.z));
            a3 += ((v0.w + v1.w) + (v2.w + v3.w)) + ((v4.w + v5.w) + (v6.w + v7.w));
            e += 8;
        }
        if (e < end) {
#pragma unroll
            for (int j = 0; j < 7; ++j) {
                int a = e + j;
                bool vld = a < end;
                int s = csr[vld ? a : beg];
                float m = vld ? 1.f : 0.f;
                float4 v = X4[(size_t)s * 32 + fl];
                a0 += m * v.x; a1 += m * v.y; a2 += m * v.z; a3 += m * v.w;
            }
        }
        ushort4 H, L;
        H.x = f2bf(a0); L.x = f2bf(a0 - bf2f(H.x));
        H.y = f2bf(a1); L.y = f2bf(a1 - bf2f(H.y));
        H.z = f2bf(a2); L.z = f2bf(a2 - bf2f(H.z));
        H.w = f2bf(a3); L.w = f2bf(a3 - bf2f(H.w));
        *reinterpret_cast<ushort4*>(&ldsH[row * LDA + fl * 4]) = H;
        *reinterpret_cast<ushort4*>(&ldsL[row * LDA + fl * 4]) = L;
    }
    __syncthreads();

    // ---------- phase 2: MFMA GEMM from LDS ----------
    int c16 = lane & 15, kq = (lane >> 4) * 8;
    int col = wid * 16 + c16;

    bf16x8 wh[K / 32], wl[K / 32];
#pragma unroll
    for (int ks = 0; ks < K / 32; ++ks) {
        wh[ks] = *reinterpret_cast<const bf16x8*>(WhT + (size_t)col * K + ks * 32 + kq);
        wl[ks] = *reinterpret_cast<const bf16x8*>(WlT + (size_t)col * K + ks * 32 + kq);
    }
    float bb = bias[col];

#pragma unroll
    for (int rt = 0; rt < 4; ++rt) {
        f32x4 acc = {0.f, 0.f, 0.f, 0.f};
        int abase = (rt * 16 + c16) * LDA + kq;
#pragma unroll
        for (int ks = 0; ks < K / 32; ++ks) {
            bf16x8 ah = *reinterpret_cast<const bf16x8*>(ldsH + abase + ks * 32);
            bf16x8 al = *reinterpret_cast<const bf16x8*>(ldsL + abase + ks * 32);
            acc = __builtin_amdgcn_mfma_f32_16x16x32_bf16(ah, wh[ks], acc, 0, 0, 0);
            acc = __builtin_amdgcn_mfma_f32_16x16x32_bf16(ah, wl[ks], acc, 0, 0, 0);
            acc = __builtin_amdgcn_mfma_f32_16x16x32_bf16(al, wh[ks], acc, 0, 0, 0);
        }
#pragma unroll
        for (int r = 0; r < 4; ++r) {
            int gr = row0 + rt * 16 + (lane >> 4) * 4 + r;
            if (gr < M) {
                float d = dinv[gr];
                float po = post ? d : 1.0f;
                float v = fmaxf(acc[r] * d + bb, 0.f) * po;
                C[(size_t)gr * 128 + col] = v;
            }
        }
    }
}

// ---------------- Final FC: one wave per pair; lane carries 4 concat elements ----------------
// lanes 0-31: HL[l0] (float4 each = 128 floats), lanes 32-63: HR[l1]. One float4 gather
// per lane + 2 cached fcW float4 loads; full-wave shuffle reduce covers all 256 elements.

__global__ void fc_kernel(const float* __restrict__ H3, const int* __restrict__ label,
                          const float* __restrict__ fcW, const float* __restrict__ fcb,
                          float* __restrict__ out, int P, int N) {
    int w = blockIdx.x * (blockDim.x >> 6) + (threadIdx.x >> 6);
    int lane = threadIdx.x & 63;
    if (w >= P) return;
    int l0 = label[2 * w], l1 = label[2 * w + 1] + N;
    int half = lane >> 5;   // 0: ligand row, 1: receptor row
    int q = lane & 31;      // float4 slot within the 128-f32 row
    size_t row = half ? (size_t)l1 : (size_t)l0;
    float4 c = *reinterpret_cast<const float4*>(H3 + row * 128 + q * 4);
    int k0 = half * 128 + q * 4;  // concat index of c.x
    // fcW is [256][2] row-major: 8 consecutive floats cover k0..k0+3, both outputs
    float4 w01 = *reinterpret_cast<const float4*>(fcW + k0 * 2);
    float4 w23 = *reinterpret_cast<const float4*>(fcW + k0 * 2 + 4);
    float a0 = c.x * w01.x + c.y * w01.z + c.z * w23.x + c.w * w23.z;
    float a1 = c.x * w01.y + c.y * w01.w + c.z * w23.y + c.w * w23.w;
#pragma unroll
    for (int o = 32; o; o >>= 1) {
        a0 += __shfl_xor(a0, o);
        a1 += __shfl_xor(a1, o);
    }
    if (lane == 0) {
        out[2 * w]     = fmaxf(a0 + fcb[0], 0.f);
        out[2 * w + 1] = fmaxf(a1 + fcb[1], 0.f);
    }
}

// ---------------- launch ----------------

extern "C" void kernel_launch(void* const* d_in, const int* in_sizes, int n_in,
                              void* d_out, int out_size, void* d_ws, size_t ws_size,
                              hipStream_t stream) {
    const float* x1   = (const float*)d_in[0];
    const int*   e1   = (const int*)d_in[1];
    const float* x2   = (const float*)d_in[2];
    const int*   e2   = (const int*)d_in[3];
    const int*   label= (const int*)d_in[4];
    const float* W0   = (const float*)d_in[5];
    const float* b0   = (const float*)d_in[6];
    const float* W1   = (const float*)d_in[7];
    const float* b1   = (const float*)d_in[8];
    const float* W2   = (const float*)d_in[9];
    const float* b2   = (const float*)d_in[10];
    const float* fcW  = (const float*)d_in[11];
    const float* fcb  = (const float*)d_in[12];
    float* out = (float*)d_out;

    const int N = in_sizes[0] / 64;
    const int E = in_sizes[1] / 2;
    const int P = in_sizes[4] / 2;
    const int NN = 2 * N;
    const int NB = (NN + 255) / 256;
    const int GB = (NN + 63) / 64;  // fused blocks (64 rows each)

    char* ws = (char*)d_ws;
    size_t off = 0;
    auto alloc = [&](size_t bytes) -> void* {
        void* p = ws + off;
        off += (bytes + 255) & ~(size_t)255;
        return p;
    };
    int*   cnt      = (int*)alloc((size_t)NN * 4);
    int*   rowptr   = (int*)alloc((size_t)(NN + 1) * 4);
    float* dinv     = (float*)alloc((size_t)NN * 4);
    int*   csr      = (int*)alloc((size_t)2 * E * 4);
    int*   blockSums= (int*)alloc((size_t)NB * 4);
    int*   blockOff = (int*)alloc((size_t)NB * 4);
    float* bufA     = (float*)alloc((size_t)NN * 128 * 4);  // X0 ([NN][64]) then H2
    float* bufB     = (float*)alloc((size_t)NN * 128 * 4);  // H1 then H3
    unsigned short* W0h = (unsigned short*)alloc(64 * 128 * 2);
    unsigned short* W0l = (unsigned short*)alloc(64 * 128 * 2);
    unsigned short* W1h = (unsigned short*)alloc(128 * 128 * 2);
    unsigned short* W1l = (unsigned short*)alloc(128 * 128 * 2);
    unsigned short* W2h = (unsigned short*)alloc(128 * 128 * 2);
    unsigned short* W2l = (unsigned short*)alloc(128 * 128 * 2);

    prep_weights<<<3, 256, 0, stream>>>(W0, W1, W2, W0h, W0l, W1h, W1l, W2h, W2l);

    // CSR build (once, union graph)
    hipMemsetAsync(cnt, 0, (size_t)NN * 4, stream);
    histU_kernel<<<(2 * E + 255) / 256, 256, 0, stream>>>(e1 + E, e2 + E, cnt, E, N);
    block_reduce_kernel<<<NB, 256, 0, stream>>>(cnt, dinv, blockSums, NN);
    scan_sums_kernel<<<1, 1024, 0, stream>>>(blockSums, blockOff, NB, rowptr, NN);
    scan_write_kernel<<<NB, 256, 0, stream>>>(cnt, blockOff, rowptr, NN);
    placeU_kernel<<<(2 * E + 255) / 256, 256, 0, stream>>>(e1, e1 + E, e2, e2 + E,
                                                           rowptr, cnt, csr, E, N);
    // layer 0: prescale into X0 (bufA), fused agg+GEMM 64->128 into bufB
    prescale_kernel<<<(NN * 16 + 255) / 256, 256, 0, stream>>>(x1, x2, dinv, bufA, NN, N);
    fused64_agg_gemm<<<GB, 512, 0, stream>>>(bufA, rowptr, csr, W0h, W0l, b0, dinv, 1,
                                             bufB, NN);
    // layer 1: bufB -> bufA
    fused128_agg_gemm<<<GB, 512, 0, stream>>>(bufB, rowptr, csr, W1h, W1l, b1, dinv, 1,
                                              bufA, NN);
    // layer 2 (no post-scale): bufA -> bufB (H3)
    fused128_agg_gemm<<<GB, 512, 0, stream>>>(bufA, rowptr, csr, W2h, W2l, b2, dinv, 0,
                                              bufB, NN);

    fc_kernel<<<(P + 3) / 4, 256, 0, stream>>>(bufB, label, fcW, fcb, out, P, N);
}

// Round 14
// 532.491 us; speedup vs baseline: 1.0835x; 1.0164x over previous
//
#include <hip/hip_runtime.h>
#include <math.h>

typedef __attribute__((ext_vector_type(8))) short bf16x8;
typedef __attribute__((ext_vector_type(4))) float f32x4;

__device__ inline unsigned short f2bf(float f) {
    unsigned int u = __float_as_uint(f);
    unsigned int r = u + 0x7fffu + ((u >> 16) & 1u);
    return (unsigned short)(r >> 16);
}
__device__ inline float bf2f(unsigned short b) {
    return __uint_as_float(((unsigned int)b) << 16);
}

// ---------------- CSR build (union graph: nodes [0,N)=g1, [N,2N)=g2) ----------------

__global__ void histU_kernel(const int* __restrict__ d1, const int* __restrict__ d2,
                             int* __restrict__ cnt, int E, int N) {
    int i = blockIdx.x * blockDim.x + threadIdx.x;
    if (i < E) atomicAdd(&cnt[d1[i]], 1);
    else if (i < 2 * E) atomicAdd(&cnt[N + d2[i - E]], 1);
}

__global__ __launch_bounds__(256) void block_reduce_kernel(const int* __restrict__ cnt,
                                                           float* __restrict__ dinv,
                                                           int* __restrict__ blockSums, int NN) {
    int i = blockIdx.x * 256 + threadIdx.x;
    int v = 0;
    if (i < NN) {
        v = cnt[i];
        dinv[i] = 1.0f / sqrtf((float)(v + 1));  // +1 self loop
    }
    int s = v;
#pragma unroll
    for (int o = 32; o; o >>= 1) s += __shfl_down(s, o);
    __shared__ int ws[4];
    if ((threadIdx.x & 63) == 0) ws[threadIdx.x >> 6] = s;
    __syncthreads();
    if (threadIdx.x == 0) blockSums[blockIdx.x] = ws[0] + ws[1] + ws[2] + ws[3];
}

__global__ __launch_bounds__(1024) void scan_sums_kernel(const int* __restrict__ blockSums,
                                                         int* __restrict__ blockOff, int nb,
                                                         int* __restrict__ rowptr, int NN) {
    __shared__ int sh[1024];
    int t = threadIdx.x;
    int v = (t < nb) ? blockSums[t] : 0;
    sh[t] = v;
    __syncthreads();
    for (int o = 1; o < 1024; o <<= 1) {
        int u = (t >= o) ? sh[t - o] : 0;
        __syncthreads();
        sh[t] += u;
        __syncthreads();
    }
    if (t < nb) blockOff[t] = sh[t] - v;
    if (t == 1023) rowptr[NN] = sh[1023];
}

__global__ __launch_bounds__(256) void scan_write_kernel(const int* __restrict__ cnt,
                                                         const int* __restrict__ blockOff,
                                                         int* __restrict__ rowptr, int NN) {
    __shared__ int sh[256];
    int i = blockIdx.x * 256 + threadIdx.x;
    int t = threadIdx.x;
    int v = (i < NN) ? cnt[i] : 0;
    sh[t] = v;
    __syncthreads();
    for (int o = 1; o < 256; o <<= 1) {
        int u = (t >= o) ? sh[t - o] : 0;
        __syncthreads();
        sh[t] += u;
        __syncthreads();
    }
    if (i < NN) rowptr[i] = blockOff[blockIdx.x] + sh[t] - v;
}

__global__ void placeU_kernel(const int* __restrict__ s1, const int* __restrict__ d1,
                              const int* __restrict__ s2, const int* __restrict__ d2,
                              const int* __restrict__ rowptr, int* __restrict__ cnt,
                              int* __restrict__ csr, int E, int N) {
    int i = blockIdx.x * blockDim.x + threadIdx.x;
    int s, d;
    if (i < E)          { s = s1[i];         d = d1[i]; }
    else if (i < 2 * E) { s = s2[i - E] + N; d = d2[i - E] + N; }
    else return;
    int p = atomicSub(&cnt[d], 1);  // old count, 1..deg; drains cnt to 0
    csr[rowptr[d] + p - 1] = s;
}

// ---------------- Weight prep: W[K][128] f32 -> WhT/WlT [128][K] bf16 ----------------

__global__ void prep_weights(const float* __restrict__ W0, const float* __restrict__ W1,
                             const float* __restrict__ W2,
                             unsigned short* __restrict__ W0h, unsigned short* __restrict__ W0l,
                             unsigned short* __restrict__ W1h, unsigned short* __restrict__ W1l,
                             unsigned short* __restrict__ W2h, unsigned short* __restrict__ W2l) {
    const float* W; unsigned short *Wh, *Wl; int K;
    if (blockIdx.x == 0)      { W = W0; Wh = W0h; Wl = W0l; K = 64; }
    else if (blockIdx.x == 1) { W = W1; Wh = W1h; Wl = W1l; K = 128; }
    else                      { W = W2; Wh = W2h; Wl = W2l; K = 128; }
    for (int i = threadIdx.x; i < K * 128; i += 256) {
        int k = i >> 7, c = i & 127;
        float v = W[i];
        unsigned short h = f2bf(v);
        unsigned short l = f2bf(v - bf2f(h));
        Wh[c * K + k] = h;
        Wl[c * K + k] = l;
    }
}

// ---- Prescale: X0[i] = dinv[i] * x(i), unified [NN][64] f32 (coalesced) ----

__global__ void prescale_kernel(const float* __restrict__ x1, const float* __restrict__ x2,
                                const float* __restrict__ dinv, float* __restrict__ X0, int NN,
                                int N) {
    int i = blockIdx.x * blockDim.x + threadIdx.x;  // over NN*16 float4
    if (i >= NN * 16) return;
    int r = i >> 4;
    const float4* src = (r < N) ? (const float4*)(x1) + i
                                : (const float4*)(x2) + (i - N * 16);
    float4 v = *src;
    float d = dinv[r];
    v.x *= d; v.y *= d; v.z *= d; v.w *= d;
    reinterpret_cast<float4*>(X0)[i] = v;
}

// ---- Fused agg + MFMA GEMM (K=64). Block = 64 rows, 512 thr = 8 waves.
// Gather: 4 nodes per wave (16-lane groups, float4/lane = full 64-f32 row per group).

__global__ __launch_bounds__(512) void fused64_agg_gemm(
    const float* __restrict__ X, const int* __restrict__ rowptr,
    const int* __restrict__ csr,
    const unsigned short* __restrict__ WhT, const unsigned short* __restrict__ WlT,
    const float* __restrict__ bias, const float* __restrict__ dinv, int post,
    float* __restrict__ C, int M) {
    const int K = 64;
    const int LDA = K + 8;
    __shared__ unsigned short ldsH[64 * LDA];
    __shared__ unsigned short ldsL[64 * LDA];

    int t = threadIdx.x;
    int lane = t & 63, wid = t >> 6;
    int row0 = blockIdx.x * 64;

    const float4* X4 = (const float4*)X;  // 16 float4 per row
    int grp = lane >> 4;   // 0..3
    int fl = lane & 15;    // features fl*4 .. fl*4+3

    // ---------- phase 1: aggregation (4 nodes per wave pass, 2 passes) ----------
    for (int rr = 0; rr < 2; ++rr) {
        int row = wid * 8 + rr * 4 + grp;
        int g = row0 + row; if (g >= M) g = M - 1;
        int beg = rowptr[g], end = rowptr[g + 1];
        float4 s4 = X4[(size_t)g * 16 + fl];
        float a0 = s4.x, a1 = s4.y, a2 = s4.z, a3 = s4.w;
        int e = beg;
        while (end - e >= 8) {  // per-group divergence via exec mask; loads stay clean
            int s0 = csr[e], s1 = csr[e + 1], s2 = csr[e + 2], s3 = csr[e + 3];
            int s4i = csr[e + 4], s5 = csr[e + 5], s6 = csr[e + 6], s7 = csr[e + 7];
            float4 v0 = X4[(size_t)s0 * 16 + fl];
            float4 v1 = X4[(size_t)s1 * 16 + fl];
            float4 v2 = X4[(size_t)s2 * 16 + fl];
            float4 v3 = X4[(size_t)s3 * 16 + fl];
            float4 v4 = X4[(size_t)s4i * 16 + fl];
            float4 v5 = X4[(size_t)s5 * 16 + fl];
            float4 v6 = X4[(size_t)s6 * 16 + fl];
            float4 v7 = X4[(size_t)s7 * 16 + fl];
            a0 += ((v0.x + v1.x) + (v2.x + v3.x)) + ((v4.x + v5.x) + (v6.x + v7.x));
            a1 += ((v0.y + v1.y) + (v2.y + v3.y)) + ((v4.y + v5.y) + (v6.y + v7.y));
            a2 += ((v0.z + v1.z) + (v2.z + v3.z)) + ((v4.z + v5.z) + (v6.z + v7.z));
            a3 += ((v0.w + v1.w) + (v2.w + v3.w)) + ((v4.w + v5.w) + (v6.w + v7.w));
            e += 8;
        }
        if (e < end) {  // masked tail, up to 7 in flight
#pragma unroll
            for (int j = 0; j < 7; ++j) {
                int a = e + j;
                bool vld = a < end;
                int s = csr[vld ? a : beg];
                float m = vld ? 1.f : 0.f;
                float4 v = X4[(size_t)s * 16 + fl];
                a0 += m * v.x; a1 += m * v.y; a2 += m * v.z; a3 += m * v.w;
            }
        }
        ushort4 H, L;
        H.x = f2bf(a0); L.x = f2bf(a0 - bf2f(H.x));
        H.y = f2bf(a1); L.y = f2bf(a1 - bf2f(H.y));
        H.z = f2bf(a2); L.z = f2bf(a2 - bf2f(H.z));
        H.w = f2bf(a3); L.w = f2bf(a3 - bf2f(H.w));
        *reinterpret_cast<ushort4*>(&ldsH[row * LDA + fl * 4]) = H;
        *reinterpret_cast<ushort4*>(&ldsL[row * LDA + fl * 4]) = L;
    }
    __syncthreads();

    // ---------- phase 2: MFMA GEMM from LDS ----------
    int c16 = lane & 15, kq = (lane >> 4) * 8;
    int col = wid * 16 + c16;

    bf16x8 wh[K / 32], wl[K / 32];
#pragma unroll
    for (int ks = 0; ks < K / 32; ++ks) {
        wh[ks] = *reinterpret_cast<const bf16x8*>(WhT + (size_t)col * K + ks * 32 + kq);
        wl[ks] = *reinterpret_cast<const bf16x8*>(WlT + (size_t)col * K + ks * 32 + kq);
    }
    float bb = bias[col];

#pragma unroll
    for (int rt = 0; rt < 4; ++rt) {
        f32x4 acc = {0.f, 0.f, 0.f, 0.f};
        int abase = (rt * 16 + c16) * LDA + kq;
#pragma unroll
        for (int ks = 0; ks < K / 32; ++ks) {
            bf16x8 ah = *reinterpret_cast<const bf16x8*>(ldsH + abase + ks * 32);
            bf16x8 al = *reinterpret_cast<const bf16x8*>(ldsL + abase + ks * 32);
            acc = __builtin_amdgcn_mfma_f32_16x16x32_bf16(ah, wh[ks], acc, 0, 0, 0);
            acc = __builtin_amdgcn_mfma_f32_16x16x32_bf16(ah, wl[ks], acc, 0, 0, 0);
            acc = __builtin_amdgcn_mfma_f32_16x16x32_bf16(al, wh[ks], acc, 0, 0, 0);
        }
#pragma unroll
        for (int r = 0; r < 4; ++r) {
            int gr = row0 + rt * 16 + (lane >> 4) * 4 + r;
            if (gr < M) {
                float d = dinv[gr];
                float po = post ? d : 1.0f;
                float v = fmaxf(acc[r] * d + bb, 0.f) * po;
                C[(size_t)gr * 128 + col] = v;
            }
        }
    }
}

// ---- Fused agg + MFMA GEMM (K=128), BM=32 tiles (fine-grained: less tail/straggler).
// Gather: 2 nodes per wave (32-lane groups, float4/lane); 8 waves x 4 rows = 32 rows.

__global__ __launch_bounds__(512) void fused128_agg_gemm(
    const float* __restrict__ X, const int* __restrict__ rowptr,
    const int* __restrict__ csr,
    const unsigned short* __restrict__ WhT, const unsigned short* __restrict__ WlT,
    const float* __restrict__ bias, const float* __restrict__ dinv, int post,
    float* __restrict__ C, int M) {
    const int K = 128;
    const int LDA = K + 8;
    __shared__ unsigned short ldsH[32 * LDA];
    __shared__ unsigned short ldsL[32 * LDA];

    int t = threadIdx.x;
    int lane = t & 63, wid = t >> 6;
    int row0 = blockIdx.x * 32;

    const float4* X4 = (const float4*)X;  // 32 float4 per row
    int grp = lane >> 5;   // 0..1
    int fl = lane & 31;    // features fl*4 .. fl*4+3

    // ---------- phase 1: aggregation (2 nodes per wave pass, 2 passes) ----------
    for (int rr = 0; rr < 2; ++rr) {
        int row = wid * 4 + rr * 2 + grp;
        int g = row0 + row; if (g >= M) g = M - 1;
        int beg = rowptr[g], end = rowptr[g + 1];
        float4 s4 = X4[(size_t)g * 32 + fl];
        float a0 = s4.x, a1 = s4.y, a2 = s4.z, a3 = s4.w;
        int e = beg;
        while (end - e >= 8) {  // per-group divergence via exec mask; loads stay clean
            int s0 = csr[e], s1 = csr[e + 1], s2 = csr[e + 2], s3 = csr[e + 3];
            int s4i = csr[e + 4], s5 = csr[e + 5], s6 = csr[e + 6], s7 = csr[e + 7];
            float4 v0 = X4[(size_t)s0 * 32 + fl];
            float4 v1 = X4[(size_t)s1 * 32 + fl];
            float4 v2 = X4[(size_t)s2 * 32 + fl];
            float4 v3 = X4[(size_t)s3 * 32 + fl];
            float4 v4 = X4[(size_t)s4i * 32 + fl];
            float4 v5 = X4[(size_t)s5 * 32 + fl];
            float4 v6 = X4[(size_t)s6 * 32 + fl];
            float4 v7 = X4[(size_t)s7 * 32 + fl];
            a0 += ((v0.x + v1.x) + (v2.x + v3.x)) + ((v4.x + v5.x) + (v6.x + v7.x));
            a1 += ((v0.y + v1.y) + (v2.y + v3.y)) + ((v4.y + v5.y) + (v6.y + v7.y));
            a2 += ((v0.z + v1.z) + (v2.z + v3.z)) + ((v4.z + v5.z) + (v6.z + v7.z));
            a3 += ((v0.w + v1.w) + (v2.w + v3.w)) + ((v4.w + v5.w) + (v6.w + v7.w));
            e += 8;
        }
        if (e < end) {
#pragma unroll
            for (int j = 0; j < 7; ++j) {
                int a = e + j;
                bool vld = a < end;
                int s = csr[vld ? a : beg];
                float m = vld ? 1.f : 0.f;
                float4 v = X4[(size_t)s * 32 + fl];
                a0 += m * v.x; a1 += m * v.y; a2 += m * v.z; a3 += m * v.w;
            }
        }
        ushort4 H, L;
        H.x = f2bf(a0); L.x = f2bf(a0 - bf2f(H.x));
        H.y = f2bf(a1); L.y = f2bf(a1 - bf2f(H.y));
        H.z = f2bf(a2); L.z = f2bf(a2 - bf2f(H.z));
        H.w = f2bf(a3); L.w = f2bf(a3 - bf2f(H.w));
        *reinterpret_cast<ushort4*>(&ldsH[row * LDA + fl * 4]) = H;
        *reinterpret_cast<ushort4*>(&ldsL[row * LDA + fl * 4]) = L;
    }
    __syncthreads();

    // ---------- phase 2: MFMA GEMM from LDS (2 row-tiles) ----------
    int c16 = lane & 15, kq = (lane >> 4) * 8;
    int col = wid * 16 + c16;

    bf16x8 wh[K / 32], wl[K / 32];
#pragma unroll
    for (int ks = 0; ks < K / 32; ++ks) {
        wh[ks] = *reinterpret_cast<const bf16x8*>(WhT + (size_t)col * K + ks * 32 + kq);
        wl[ks] = *reinterpret_cast<const bf16x8*>(WlT + (size_t)col * K + ks * 32 + kq);
    }
    float bb = bias[col];

#pragma unroll
    for (int rt = 0; rt < 2; ++rt) {
        f32x4 acc = {0.f, 0.f, 0.f, 0.f};
        int abase = (rt * 16 + c16) * LDA + kq;
#pragma unroll
        for (int ks = 0; ks < K / 32; ++ks) {
            bf16x8 ah = *reinterpret_cast<const bf16x8*>(ldsH + abase + ks * 32);
            bf16x8 al = *reinterpret_cast<const bf16x8*>(ldsL + abase + ks * 32);
            acc = __builtin_amdgcn_mfma_f32_16x16x32_bf16(ah, wh[ks], acc, 0, 0, 0);
            acc = __builtin_amdgcn_mfma_f32_16x16x32_bf16(ah, wl[ks], acc, 0, 0, 0);
            acc = __builtin_amdgcn_mfma_f32_16x16x32_bf16(al, wh[ks], acc, 0, 0, 0);
        }
#pragma unroll
        for (int r = 0; r < 4; ++r) {
            int gr = row0 + rt * 16 + (lane >> 4) * 4 + r;
            if (gr < M) {
                float d = dinv[gr];
                float po = post ? d : 1.0f;
                float v = fmaxf(acc[r] * d + bb, 0.f) * po;
                C[(size_t)gr * 128 + col] = v;
            }
        }
    }
}

// ---------------- Final FC: one wave per pair; lane carries 4 concat elements ----------------

__global__ void fc_kernel(const float* __restrict__ H3, const int* __restrict__ label,
                          const float* __restrict__ fcW, const float* __restrict__ fcb,
                          float* __restrict__ out, int P, int N) {
    int w = blockIdx.x * (blockDim.x >> 6) + (threadIdx.x >> 6);
    int lane = threadIdx.x & 63;
    if (w >= P) return;
    int l0 = label[2 * w], l1 = label[2 * w + 1] + N;
    int half = lane >> 5;   // 0: ligand row, 1: receptor row
    int q = lane & 31;      // float4 slot within the 128-f32 row
    size_t row = half ? (size_t)l1 : (size_t)l0;
    float4 c = *reinterpret_cast<const float4*>(H3 + row * 128 + q * 4);
    int k0 = half * 128 + q * 4;
    float4 w01 = *reinterpret_cast<const float4*>(fcW + k0 * 2);
    float4 w23 = *reinterpret_cast<const float4*>(fcW + k0 * 2 + 4);
    float a0 = c.x * w01.x + c.y * w01.z + c.z * w23.x + c.w * w23.z;
    float a1 = c.x * w01.y + c.y * w01.w + c.z * w23.y + c.w * w23.w;
#pragma unroll
    for (int o = 32; o; o >>= 1) {
        a0 += __shfl_xor(a0, o);
        a1 += __shfl_xor(a1, o);
    }
    if (lane == 0) {
        out[2 * w]     = fmaxf(a0 + fcb[0], 0.f);
        out[2 * w + 1] = fmaxf(a1 + fcb[1], 0.f);
    }
}

// ---------------- launch ----------------

extern "C" void kernel_launch(void* const* d_in, const int* in_sizes, int n_in,
                              void* d_out, int out_size, void* d_ws, size_t ws_size,
                              hipStream_t stream) {
    const float* x1   = (const float*)d_in[0];
    const int*   e1   = (const int*)d_in[1];
    const float* x2   = (const float*)d_in[2];
    const int*   e2   = (const int*)d_in[3];
    const int*   label= (const int*)d_in[4];
    const float* W0   = (const float*)d_in[5];
    const float* b0   = (const float*)d_in[6];
    const float* W1   = (const float*)d_in[7];
    const float* b1   = (const float*)d_in[8];
    const float* W2   = (const float*)d_in[9];
    const float* b2   = (const float*)d_in[10];
    const float* fcW  = (const float*)d_in[11];
    const float* fcb  = (const float*)d_in[12];
    float* out = (float*)d_out;

    const int N = in_sizes[0] / 64;
    const int E = in_sizes[1] / 2;
    const int P = in_sizes[4] / 2;
    const int NN = 2 * N;
    const int NB = (NN + 255) / 256;
    const int GB64 = (NN + 63) / 64;    // fused64 blocks (64 rows)
    const int GB128 = (NN + 31) / 32;   // fused128 blocks (32 rows, fine-grained)

    char* ws = (char*)d_ws;
    size_t off = 0;
    auto alloc = [&](size_t bytes) -> void* {
        void* p = ws + off;
        off += (bytes + 255) & ~(size_t)255;
        return p;
    };
    int*   cnt      = (int*)alloc((size_t)NN * 4);
    int*   rowptr   = (int*)alloc((size_t)(NN + 1) * 4);
    float* dinv     = (float*)alloc((size_t)NN * 4);
    int*   csr      = (int*)alloc((size_t)2 * E * 4);
    int*   blockSums= (int*)alloc((size_t)NB * 4);
    int*   blockOff = (int*)alloc((size_t)NB * 4);
    float* bufA     = (float*)alloc((size_t)NN * 128 * 4);  // X0 ([NN][64]) then H2
    float* bufB     = (float*)alloc((size_t)NN * 128 * 4);  // H1 then H3
    unsigned short* W0h = (unsigned short*)alloc(64 * 128 * 2);
    unsigned short* W0l = (unsigned short*)alloc(64 * 128 * 2);
    unsigned short* W1h = (unsigned short*)alloc(128 * 128 * 2);
    unsigned short* W1l = (unsigned short*)alloc(128 * 128 * 2);
    unsigned short* W2h = (unsigned short*)alloc(128 * 128 * 2);
    unsigned short* W2l = (unsigned short*)alloc(128 * 128 * 2);

    prep_weights<<<3, 256, 0, stream>>>(W0, W1, W2, W0h, W0l, W1h, W1l, W2h, W2l);

    // CSR build (once, union graph)
    hipMemsetAsync(cnt, 0, (size_t)NN * 4, stream);
    histU_kernel<<<(2 * E + 255) / 256, 256, 0, stream>>>(e1 + E, e2 + E, cnt, E, N);
    block_reduce_kernel<<<NB, 256, 0, stream>>>(cnt, dinv, blockSums, NN);
    scan_sums_kernel<<<1, 1024, 0, stream>>>(blockSums, blockOff, NB, rowptr, NN);
    scan_write_kernel<<<NB, 256, 0, stream>>>(cnt, blockOff, rowptr, NN);
    placeU_kernel<<<(2 * E + 255) / 256, 256, 0, stream>>>(e1, e1 + E, e2, e2 + E,
                                                           rowptr, cnt, csr, E, N);
    // layer 0: prescale into X0 (bufA), fused agg+GEMM 64->128 into bufB
    prescale_kernel<<<(NN * 16 + 255) / 256, 256, 0, stream>>>(x1, x2, dinv, bufA, NN, N);
    fused64_agg_gemm<<<GB64, 512, 0, stream>>>(bufA, rowptr, csr, W0h, W0l, b0, dinv, 1,
                                               bufB, NN);
    // layer 1: bufB -> bufA
    fused128_agg_gemm<<<GB128, 512, 0, stream>>>(bufB, rowptr, csr, W1h, W1l, b1, dinv, 1,
                                                 bufA, NN);
    // layer 2 (no post-scale): bufA -> bufB (H3)
    fused128_agg_gemm<<<GB128, 512, 0, stream>>>(bufA, rowptr, csr, W2h, W2l, b2, dinv, 0,
                                                 bufB, NN);

    fc_kernel<<<(P + 3) / 4, 256, 0, stream>>>(bufB, label, fcW, fcb, out, P, N);
}

// Round 15
// 528.685 us; speedup vs baseline: 1.0913x; 1.0072x over previous
//
#include <hip/hip_runtime.h>
#include <math.h>

typedef __attribute__((ext_vector_type(8))) short bf16x8;
typedef __attribute__((ext_vector_type(4))) float f32x4;

__device__ inline unsigned short f2bf(float f) {
    unsigned int u = __float_as_uint(f);
    unsigned int r = u + 0x7fffu + ((u >> 16) & 1u);
    return (unsigned short)(r >> 16);
}
__device__ inline float bf2f(unsigned short b) {
    return __uint_as_float(((unsigned int)b) << 16);
}

// ---------------- CSR build (union graph: nodes [0,N)=g1, [N,2N)=g2) ----------------

__global__ void histU_kernel(const int* __restrict__ d1, const int* __restrict__ d2,
                             int* __restrict__ cnt, int E, int N) {
    int i = blockIdx.x * blockDim.x + threadIdx.x;
    if (i < E) atomicAdd(&cnt[d1[i]], 1);
    else if (i < 2 * E) atomicAdd(&cnt[N + d2[i - E]], 1);
}

__global__ __launch_bounds__(256) void block_reduce_kernel(const int* __restrict__ cnt,
                                                           float* __restrict__ dinv,
                                                           int* __restrict__ blockSums, int NN) {
    int i = blockIdx.x * 256 + threadIdx.x;
    int v = 0;
    if (i < NN) {
        v = cnt[i];
        dinv[i] = 1.0f / sqrtf((float)(v + 1));  // +1 self loop
    }
    int s = v;
#pragma unroll
    for (int o = 32; o; o >>= 1) s += __shfl_down(s, o);
    __shared__ int ws[4];
    if ((threadIdx.x & 63) == 0) ws[threadIdx.x >> 6] = s;
    __syncthreads();
    if (threadIdx.x == 0) blockSums[blockIdx.x] = ws[0] + ws[1] + ws[2] + ws[3];
}

// Scan: each block self-computes its offset (sum of preceding blockSums; <=391 ints, L2),
// then does the local exclusive scan. Removes the separate single-block scan launch.
__global__ __launch_bounds__(256) void scan_write_kernel(const int* __restrict__ cnt,
                                                         const int* __restrict__ blockSums,
                                                         int* __restrict__ rowptr, int NN) {
    __shared__ int sh[256];
    __shared__ int pre[256];
    int b = blockIdx.x;
    int t = threadIdx.x;
    int ps = 0;
    for (int j = t; j < b; j += 256) ps += blockSums[j];
    pre[t] = ps;
    __syncthreads();
    for (int o = 128; o; o >>= 1) {
        if (t < o) pre[t] += pre[t + o];
        __syncthreads();
    }
    int off = pre[0];
    int i = b * 256 + t;
    int v = (i < NN) ? cnt[i] : 0;
    sh[t] = v;
    __syncthreads();
    for (int o = 1; o < 256; o <<= 1) {
        int u = (t >= o) ? sh[t - o] : 0;
        __syncthreads();
        sh[t] += u;
        __syncthreads();
    }
    if (i < NN) rowptr[i] = off + sh[t] - v;
    if (i == NN - 1) rowptr[NN] = off + sh[t];
}

__global__ void placeU_kernel(const int* __restrict__ s1, const int* __restrict__ d1,
                              const int* __restrict__ s2, const int* __restrict__ d2,
                              const int* __restrict__ rowptr, int* __restrict__ cnt,
                              int* __restrict__ csr, int E, int N) {
    int i = blockIdx.x * blockDim.x + threadIdx.x;
    int s, d;
    if (i < E)          { s = s1[i];         d = d1[i]; }
    else if (i < 2 * E) { s = s2[i - E] + N; d = d2[i - E] + N; }
    else return;
    int p = atomicSub(&cnt[d], 1);  // old count, 1..deg; drains cnt to 0
    csr[rowptr[d] + p - 1] = s;
}

// ---------------- Weight prep: W[K][128] f32 -> WhT/WlT [128][K] bf16 ----------------

__global__ void prep_weights(const float* __restrict__ W0, const float* __restrict__ W1,
                             const float* __restrict__ W2,
                             unsigned short* __restrict__ W0h, unsigned short* __restrict__ W0l,
                             unsigned short* __restrict__ W1h, unsigned short* __restrict__ W1l,
                             unsigned short* __restrict__ W2h, unsigned short* __restrict__ W2l) {
    const float* W; unsigned short *Wh, *Wl; int K;
    if (blockIdx.x == 0)      { W = W0; Wh = W0h; Wl = W0l; K = 64; }
    else if (blockIdx.x == 1) { W = W1; Wh = W1h; Wl = W1l; K = 128; }
    else                      { W = W2; Wh = W2h; Wl = W2l; K = 128; }
    for (int i = threadIdx.x; i < K * 128; i += 256) {
        int k = i >> 7, c = i & 127;
        float v = W[i];
        unsigned short h = f2bf(v);
        unsigned short l = f2bf(v - bf2f(h));
        Wh[c * K + k] = h;
        Wl[c * K + k] = l;
    }
}

// ---- Prescale: X0[i] = dinv[i] * x(i), unified [NN][64] f32 (coalesced) ----

__global__ void prescale_kernel(const float* __restrict__ x1, const float* __restrict__ x2,
                                const float* __restrict__ dinv, float* __restrict__ X0, int NN,
                                int N) {
    int i = blockIdx.x * blockDim.x + threadIdx.x;  // over NN*16 float4
    if (i >= NN * 16) return;
    int r = i >> 4;
    const float4* src = (r < N) ? (const float4*)(x1) + i
                                : (const float4*)(x2) + (i - N * 16);
    float4 v = *src;
    float d = dinv[r];
    v.x *= d; v.y *= d; v.z *= d; v.w *= d;
    reinterpret_cast<float4*>(X0)[i] = v;
}

// ---- Fused agg + MFMA GEMM (K=64), BM=32 tiles. 512 thr = 8 waves.
// Gather: 4 nodes per wave (16-lane groups, float4/lane = full 64-f32 row per group).

__global__ __launch_bounds__(512) void fused64_agg_gemm(
    const float* __restrict__ X, const int* __restrict__ rowptr,
    const int* __restrict__ csr,
    const unsigned short* __restrict__ WhT, const unsigned short* __restrict__ WlT,
    const float* __restrict__ bias, const float* __restrict__ dinv, int post,
    float* __restrict__ C, int M) {
    const int K = 64;
    const int LDA = K + 8;
    __shared__ unsigned short ldsH[32 * LDA];
    __shared__ unsigned short ldsL[32 * LDA];

    int t = threadIdx.x;
    int lane = t & 63, wid = t >> 6;
    int row0 = blockIdx.x * 32;

    const float4* X4 = (const float4*)X;  // 16 float4 per row
    int grp = lane >> 4;   // 0..3
    int fl = lane & 15;    // features fl*4 .. fl*4+3

    // ---------- phase 1: aggregation (4 nodes per wave, 1 pass) ----------
    {
        int row = wid * 4 + grp;
        int g = row0 + row; if (g >= M) g = M - 1;
        int beg = rowptr[g], end = rowptr[g + 1];
        float4 s4 = X4[(size_t)g * 16 + fl];
        float a0 = s4.x, a1 = s4.y, a2 = s4.z, a3 = s4.w;
        int e = beg;
        while (end - e >= 8) {  // per-group divergence via exec mask; loads stay clean
            int s0 = csr[e], s1 = csr[e + 1], s2 = csr[e + 2], s3 = csr[e + 3];
            int s4i = csr[e + 4], s5 = csr[e + 5], s6 = csr[e + 6], s7 = csr[e + 7];
            float4 v0 = X4[(size_t)s0 * 16 + fl];
            float4 v1 = X4[(size_t)s1 * 16 + fl];
            float4 v2 = X4[(size_t)s2 * 16 + fl];
            float4 v3 = X4[(size_t)s3 * 16 + fl];
            float4 v4 = X4[(size_t)s4i * 16 + fl];
            float4 v5 = X4[(size_t)s5 * 16 + fl];
            float4 v6 = X4[(size_t)s6 * 16 + fl];
            float4 v7 = X4[(size_t)s7 * 16 + fl];
            a0 += ((v0.x + v1.x) + (v2.x + v3.x)) + ((v4.x + v5.x) + (v6.x + v7.x));
            a1 += ((v0.y + v1.y) + (v2.y + v3.y)) + ((v4.y + v5.y) + (v6.y + v7.y));
            a2 += ((v0.z + v1.z) + (v2.z + v3.z)) + ((v4.z + v5.z) + (v6.z + v7.z));
            a3 += ((v0.w + v1.w) + (v2.w + v3.w)) + ((v4.w + v5.w) + (v6.w + v7.w));
            e += 8;
        }
        if (e < end) {  // masked tail, up to 7 in flight
#pragma unroll
            for (int j = 0; j < 7; ++j) {
                int a = e + j;
                bool vld = a < end;
                int s = csr[vld ? a : beg];
                float m = vld ? 1.f : 0.f;
                float4 v = X4[(size_t)s * 16 + fl];
                a0 += m * v.x; a1 += m * v.y; a2 += m * v.z; a3 += m * v.w;
            }
        }
        ushort4 H, L;
        H.x = f2bf(a0); L.x = f2bf(a0 - bf2f(H.x));
        H.y = f2bf(a1); L.y = f2bf(a1 - bf2f(H.y));
        H.z = f2bf(a2); L.z = f2bf(a2 - bf2f(H.z));
        H.w = f2bf(a3); L.w = f2bf(a3 - bf2f(H.w));
        *reinterpret_cast<ushort4*>(&ldsH[row * LDA + fl * 4]) = H;
        *reinterpret_cast<ushort4*>(&ldsL[row * LDA + fl * 4]) = L;
    }
    __syncthreads();

    // ---------- phase 2: MFMA GEMM from LDS (2 row-tiles) ----------
    int c16 = lane & 15, kq = (lane >> 4) * 8;
    int col = wid * 16 + c16;

    bf16x8 wh[K / 32], wl[K / 32];
#pragma unroll
    for (int ks = 0; ks < K / 32; ++ks) {
        wh[ks] = *reinterpret_cast<const bf16x8*>(WhT + (size_t)col * K + ks * 32 + kq);
        wl[ks] = *reinterpret_cast<const bf16x8*>(WlT + (size_t)col * K + ks * 32 + kq);
    }
    float bb = bias[col];

#pragma unroll
    for (int rt = 0; rt < 2; ++rt) {
        f32x4 acc = {0.f, 0.f, 0.f, 0.f};
        int abase = (rt * 16 + c16) * LDA + kq;
#pragma unroll
        for (int ks = 0; ks < K / 32; ++ks) {
            bf16x8 ah = *reinterpret_cast<const bf16x8*>(ldsH + abase + ks * 32);
            bf16x8 al = *reinterpret_cast<const bf16x8*>(ldsL + abase + ks * 32);
            acc = __builtin_amdgcn_mfma_f32_16x16x32_bf16(ah, wh[ks], acc, 0, 0, 0);
            acc = __builtin_amdgcn_mfma_f32_16x16x32_bf16(ah, wl[ks], acc, 0, 0, 0);
            acc = __builtin_amdgcn_mfma_f32_16x16x32_bf16(al, wh[ks], acc, 0, 0, 0);
        }
#pragma unroll
        for (int r = 0; r < 4; ++r) {
            int gr = row0 + rt * 16 + (lane >> 4) * 4 + r;
            if (gr < M) {
                float d = dinv[gr];
                float po = post ? d : 1.0f;
                float v = fmaxf(acc[r] * d + bb, 0.f) * po;
                C[(size_t)gr * 128 + col] = v;
            }
        }
    }
}

// ---- Fused agg + MFMA GEMM (K=128), BM=32 tiles (fine-grained: less tail/straggler).
// Gather: 2 nodes per wave (32-lane groups, float4/lane); 8 waves x 4 rows = 32 rows.

__global__ __launch_bounds__(512) void fused128_agg_gemm(
    const float* __restrict__ X, const int* __restrict__ rowptr,
    const int* __restrict__ csr,
    const unsigned short* __restrict__ WhT, const unsigned short* __restrict__ WlT,
    const float* __restrict__ bias, const float* __restrict__ dinv, int post,
    float* __restrict__ C, int M) {
    const int K = 128;
    const int LDA = K + 8;
    __shared__ unsigned short ldsH[32 * LDA];
    __shared__ unsigned short ldsL[32 * LDA];

    int t = threadIdx.x;
    int lane = t & 63, wid = t >> 6;
    int row0 = blockIdx.x * 32;

    const float4* X4 = (const float4*)X;  // 32 float4 per row
    int grp = lane >> 5;   // 0..1
    int fl = lane & 31;    // features fl*4 .. fl*4+3

    // ---------- phase 1: aggregation (2 nodes per wave pass, 2 passes) ----------
    for (int rr = 0; rr < 2; ++rr) {
        int row = wid * 4 + rr * 2 + grp;
        int g = row0 + row; if (g >= M) g = M - 1;
        int beg = rowptr[g], end = rowptr[g + 1];
        float4 s4 = X4[(size_t)g * 32 + fl];
        float a0 = s4.x, a1 = s4.y, a2 = s4.z, a3 = s4.w;
        int e = beg;
        while (end - e >= 8) {  // per-group divergence via exec mask; loads stay clean
            int s0 = csr[e], s1 = csr[e + 1], s2 = csr[e + 2], s3 = csr[e + 3];
            int s4i = csr[e + 4], s5 = csr[e + 5], s6 = csr[e + 6], s7 = csr[e + 7];
            float4 v0 = X4[(size_t)s0 * 32 + fl];
            float4 v1 = X4[(size_t)s1 * 32 + fl];
            float4 v2 = X4[(size_t)s2 * 32 + fl];
            float4 v3 = X4[(size_t)s3 * 32 + fl];
            float4 v4 = X4[(size_t)s4i * 32 + fl];
            float4 v5 = X4[(size_t)s5 * 32 + fl];
            float4 v6 = X4[(size_t)s6 * 32 + fl];
            float4 v7 = X4[(size_t)s7 * 32 + fl];
            a0 += ((v0.x + v1.x) + (v2.x + v3.x)) + ((v4.x + v5.x) + (v6.x + v7.x));
            a1 += ((v0.y + v1.y) + (v2.y + v3.y)) + ((v4.y + v5.y) + (v6.y + v7.y));
            a2 += ((v0.z + v1.z) + (v2.z + v3.z)) + ((v4.z + v5.z) + (v6.z + v7.z));
            a3 += ((v0.w + v1.w) + (v2.w + v3.w)) + ((v4.w + v5.w) + (v6.w + v7.w));
            e += 8;
        }
        if (e < end) {
#pragma unroll
            for (int j = 0; j < 7; ++j) {
                int a = e + j;
                bool vld = a < end;
                int s = csr[vld ? a : beg];
                float m = vld ? 1.f : 0.f;
                float4 v = X4[(size_t)s * 32 + fl];
                a0 += m * v.x; a1 += m * v.y; a2 += m * v.z; a3 += m * v.w;
            }
        }
        ushort4 H, L;
        H.x = f2bf(a0); L.x = f2bf(a0 - bf2f(H.x));
        H.y = f2bf(a1); L.y = f2bf(a1 - bf2f(H.y));
        H.z = f2bf(a2); L.z = f2bf(a2 - bf2f(H.z));
        H.w = f2bf(a3); L.w = f2bf(a3 - bf2f(H.w));
        *reinterpret_cast<ushort4*>(&ldsH[row * LDA + fl * 4]) = H;
        *reinterpret_cast<ushort4*>(&ldsL[row * LDA + fl * 4]) = L;
    }
    __syncthreads();

    // ---------- phase 2: MFMA GEMM from LDS (2 row-tiles) ----------
    int c16 = lane & 15, kq = (lane >> 4) * 8;
    int col = wid * 16 + c16;

    bf16x8 wh[K / 32], wl[K / 32];
#pragma unroll
    for (int ks = 0; ks < K / 32; ++ks) {
        wh[ks] = *reinterpret_cast<const bf16x8*>(WhT + (size_t)col * K + ks * 32 + kq);
        wl[ks] = *reinterpret_cast<const bf16x8*>(WlT + (size_t)col * K + ks * 32 + kq);
    }
    float bb = bias[col];

#pragma unroll
    for (int rt = 0; rt < 2; ++rt) {
        f32x4 acc = {0.f, 0.f, 0.f, 0.f};
        int abase = (rt * 16 + c16) * LDA + kq;
#pragma unroll
        for (int ks = 0; ks < K / 32; ++ks) {
            bf16x8 ah = *reinterpret_cast<const bf16x8*>(ldsH + abase + ks * 32);
            bf16x8 al = *reinterpret_cast<const bf16x8*>(ldsL + abase + ks * 32);
            acc = __builtin_amdgcn_mfma_f32_16x16x32_bf16(ah, wh[ks], acc, 0, 0, 0);
            acc = __builtin_amdgcn_mfma_f32_16x16x32_bf16(ah, wl[ks], acc, 0, 0, 0);
            acc = __builtin_amdgcn_mfma_f32_16x16x32_bf16(al, wh[ks], acc, 0, 0, 0);
        }
#pragma unroll
        for (int r = 0; r < 4; ++r) {
            int gr = row0 + rt * 16 + (lane >> 4) * 4 + r;
            if (gr < M) {
                float d = dinv[gr];
                float po = post ? d : 1.0f;
                float v = fmaxf(acc[r] * d + bb, 0.f) * po;
                C[(size_t)gr * 128 + col] = v;
            }
        }
    }
}

// ---------------- Final FC: one wave per pair; lane carries 4 concat elements ----------------

__global__ void fc_kernel(const float* __restrict__ H3, const int* __restrict__ label,
                          const float* __restrict__ fcW, const float* __restrict__ fcb,
                          float* __restrict__ out, int P, int N) {
    int w = blockIdx.x * (blockDim.x >> 6) + (threadIdx.x >> 6);
    int lane = threadIdx.x & 63;
    if (w >= P) return;
    int l0 = label[2 * w], l1 = label[2 * w + 1] + N;
    int half = lane >> 5;   // 0: ligand row, 1: receptor row
    int q = lane & 31;      // float4 slot within the 128-f32 row
    size_t row = half ? (size_t)l1 : (size_t)l0;
    float4 c = *reinterpret_cast<const float4*>(H3 + row * 128 + q * 4);
    int k0 = half * 128 + q * 4;
    float4 w01 = *reinterpret_cast<const float4*>(fcW + k0 * 2);
    float4 w23 = *reinterpret_cast<const float4*>(fcW + k0 * 2 + 4);
    float a0 = c.x * w01.x + c.y * w01.z + c.z * w23.x + c.w * w23.z;
    float a1 = c.x * w01.y + c.y * w01.w + c.z * w23.y + c.w * w23.w;
#pragma unroll
    for (int o = 32; o; o >>= 1) {
        a0 += __shfl_xor(a0, o);
        a1 += __shfl_xor(a1, o);
    }
    if (lane == 0) {
        out[2 * w]     = fmaxf(a0 + fcb[0], 0.f);
        out[2 * w + 1] = fmaxf(a1 + fcb[1], 0.f);
    }
}

// ---------------- launch ----------------

extern "C" void kernel_launch(void* const* d_in, const int* in_sizes, int n_in,
                              void* d_out, int out_size, void* d_ws, size_t ws_size,
                              hipStream_t stream) {
    const float* x1   = (const float*)d_in[0];
    const int*   e1   = (const int*)d_in[1];
    const float* x2   = (const float*)d_in[2];
    const int*   e2   = (const int*)d_in[3];
    const int*   label= (const int*)d_in[4];
    const float* W0   = (const float*)d_in[5];
    const float* b0   = (const float*)d_in[6];
    const float* W1   = (const float*)d_in[7];
    const float* b1   = (const float*)d_in[8];
    const float* W2   = (const float*)d_in[9];
    const float* b2   = (const float*)d_in[10];
    const float* fcW  = (const float*)d_in[11];
    const float* fcb  = (const float*)d_in[12];
    float* out = (float*)d_out;

    const int N = in_sizes[0] / 64;
    const int E = in_sizes[1] / 2;
    const int P = in_sizes[4] / 2;
    const int NN = 2 * N;
    const int NB = (NN + 255) / 256;
    const int GB32 = (NN + 31) / 32;    // fused blocks (32 rows, fine-grained)

    char* ws = (char*)d_ws;
    size_t off = 0;
    auto alloc = [&](size_t bytes) -> void* {
        void* p = ws + off;
        off += (bytes + 255) & ~(size_t)255;
        return p;
    };
    int*   cnt      = (int*)alloc((size_t)NN * 4);
    int*   rowptr   = (int*)alloc((size_t)(NN + 1) * 4);
    float* dinv     = (float*)alloc((size_t)NN * 4);
    int*   csr      = (int*)alloc((size_t)2 * E * 4);
    int*   blockSums= (int*)alloc((size_t)NB * 4);
    float* bufA     = (float*)alloc((size_t)NN * 128 * 4);  // X0 ([NN][64]) then H2
    float* bufB     = (float*)alloc((size_t)NN * 128 * 4);  // H1 then H3
    unsigned short* W0h = (unsigned short*)alloc(64 * 128 * 2);
    unsigned short* W0l = (unsigned short*)alloc(64 * 128 * 2);
    unsigned short* W1h = (unsigned short*)alloc(128 * 128 * 2);
    unsigned short* W1l = (unsigned short*)alloc(128 * 128 * 2);
    unsigned short* W2h = (unsigned short*)alloc(128 * 128 * 2);
    unsigned short* W2l = (unsigned short*)alloc(128 * 128 * 2);

    prep_weights<<<3, 256, 0, stream>>>(W0, W1, W2, W0h, W0l, W1h, W1l, W2h, W2l);

    // CSR build (once, union graph)
    hipMemsetAsync(cnt, 0, (size_t)NN * 4, stream);
    histU_kernel<<<(2 * E + 255) / 256, 256, 0, stream>>>(e1 + E, e2 + E, cnt, E, N);
    block_reduce_kernel<<<NB, 256, 0, stream>>>(cnt, dinv, blockSums, NN);
    scan_write_kernel<<<NB, 256, 0, stream>>>(cnt, blockSums, rowptr, NN);
    placeU_kernel<<<(2 * E + 255) / 256, 256, 0, stream>>>(e1, e1 + E, e2, e2 + E,
                                                           rowptr, cnt, csr, E, N);
    // layer 0: prescale into X0 (bufA), fused agg+GEMM 64->128 into bufB
    prescale_kernel<<<(NN * 16 + 255) / 256, 256, 0, stream>>>(x1, x2, dinv, bufA, NN, N);
    fused64_agg_gemm<<<GB32, 512, 0, stream>>>(bufA, rowptr, csr, W0h, W0l, b0, dinv, 1,
                                               bufB, NN);
    // layer 1: bufB -> bufA
    fused128_agg_gemm<<<GB32, 512, 0, stream>>>(bufB, rowptr, csr, W1h, W1l, b1, dinv, 1,
                                                bufA, NN);
    // layer 2 (no post-scale): bufA -> bufB (H3)
    fused128_agg_gemm<<<GB32, 512, 0, stream>>>(bufA, rowptr, csr, W2h, W2l, b2, dinv, 0,
                                                bufB, NN);

    fc_kernel<<<(P + 3) / 4, 256, 0, stream>>>(bufB, label, fcW, fcb, out, P, N);
}